// Round 20
// baseline (47.735 us; speedup 1.0000x reference)
//
#include <hip/hip_runtime.h>

// SigLoss: signature kernel PDE, loss = mean_a( K(X,X) + K(Y,Y) - 2 K(X,Y) ).
// A=256, L=256, D=32. One 64-lane wave per (pair,a) problem.
// R20 = R18 base (reg B-frags, double-buffered incD) with the MFMA phase
// de-serialized. R19 falsified the scan-chain hypothesis (8 vs 11 deps, same
// time); remaining suspect is per-tile serialization: dependent mfma->mfma
// acc chain + VALU-reads-MFMA-dst hazard + no cross-tile overlap at ~196
// VGPR. Fix: (1) 3 INDEPENDENT MFMAs per tile, combine = fmaf(acc2a+acc2b,
// 2^-11, acc1); (2) scan_row(block b-1) placed BETWEEN tile k's MFMA issue
// and its combine - the ~50cyc DPP/VALU chain covers the MFMA latency and
// hazard window with useful work. incD[0]/incD[1] are provably-distinct LDS
// offsets so the compiler can reorder reads/writes freely.

typedef _Float16 half8 __attribute__((ext_vector_type(8)));
typedef float f32x4_t __attribute__((ext_vector_type(4)));

#define DPP_ADD(v, ctrl, rmask)                                               \
    ((v) + __int_as_float(__builtin_amdgcn_update_dpp(                        \
               0, __float_as_int(v), (ctrl), (rmask), 0xF, true)))

#define INV2048 4.8828125e-4f

__global__ __launch_bounds__(64)
__attribute__((amdgpu_waves_per_eu(1, 1)))
void sig_pde(const float* __restrict__ X,
             const float* __restrict__ Y,
             float* __restrict__ partial) {
    const int bid = blockIdx.x;
    const int p = bid >> 8;          // 0=xx, 1=yy, 2=xy
    const int a = bid & 255;
    const float* __restrict__ U = (p == 1) ? Y : X;   // rows (i)
    const float* __restrict__ V = (p == 0) ? X : Y;   // cols (j)
    U += (size_t)a * 256 * 32;
    V += (size_t)a * 256 * 32;
    const int lane = threadIdx.x;
    const int m16 = lane & 15;
    const int g2 = (lane >> 4) * 2;

    __shared__ __attribute__((aligned(16))) float incD[2][16 * 260]; // 33.3 KB

    const float4* U4 = (const float4*)U;
    const float4* V4 = (const float4*)V;

    // ---- B fragments dY hi/lo in registers (128 VGPR), R18-verified ----
    half8 bh[16], bl[16];
#pragma unroll
    for (int t = 0; t < 16; ++t) {
        int col = t * 16 + m16;
        int cp = (col + 1 < 256) ? col + 1 : 255;   // col 255 clamps -> dY=0
        float4 lo0 = V4[col * 8 + g2], lo1 = V4[col * 8 + g2 + 1];
        float4 hi0 = V4[cp * 8 + g2],  hi1 = V4[cp * 8 + g2 + 1];
        float d[8] = {hi0.x - lo0.x, hi0.y - lo0.y, hi0.z - lo0.z, hi0.w - lo0.w,
                      hi1.x - lo1.x, hi1.y - lo1.y, hi1.z - lo1.z, hi1.w - lo1.w};
#pragma unroll
        for (int i = 0; i < 8; ++i) {
            _Float16 h = (_Float16)d[i];
            bh[t][i] = h;
            bl[t][i] = (_Float16)((d[i] - (float)h) * 2048.0f);
        }
    }

    // K row state: kp{0..3} = K[r][4*lane+s], row 0 = ones
    float kp0 = 1.0f, kp1 = 1.0f, kp2 = 1.0f, kp3 = 1.0f;

    auto loadA = [&](int blk, float4 (&dst)[4]) {
        int r0 = blk * 16 + m16;
        int r1 = (r0 + 1 < 256) ? r0 + 1 : 255;   // dX[255] := 0 (unscanned)
        dst[0] = U4[r0 * 8 + g2];
        dst[1] = U4[r0 * 8 + g2 + 1];
        dst[2] = U4[r1 * 8 + g2];
        dst[3] = U4[r1 * 8 + g2 + 1];
    };
    auto makeAhAl = [&](const float4 (&src)[4], half8& ah, half8& al) {
        float d[8] = {src[2].x - src[0].x, src[2].y - src[0].y,
                      src[2].z - src[0].z, src[2].w - src[0].w,
                      src[3].x - src[1].x, src[3].y - src[1].y,
                      src[3].z - src[1].z, src[3].w - src[1].w};
#pragma unroll
        for (int i = 0; i < 8; ++i) {
            _Float16 h = (_Float16)d[i];
            ah[i] = h;
            al[i] = (_Float16)((d[i] - (float)h) * 2048.0f);
        }
    };

    // One scan row: mv = inc[r][4l..4l+3] - 1 (the -1 folded into MFMA)
    auto scan_row = [&](float4 mv) {
        float kn = __int_as_float(__builtin_amdgcn_update_dpp(
            0, __float_as_int(kp0), 0x130 /*wave_shl:1*/, 0xF, 0xF, true));
        float c0 = fmaf(kp0, mv.x, kp1);
        float c1 = fmaf(kp1, mv.y, kp2);
        float c2 = fmaf(kp2, mv.z, kp3);
        float c3 = (lane == 63) ? 0.0f : fmaf(kp3, mv.w, kn);
        float L0 = c0, L1 = L0 + c1, L2 = L1 + c2;
        float T = L2 + c3;
        float S = T;
        S = DPP_ADD(S, 0x111, 0xF);  // row_shr:1
        S = DPP_ADD(S, 0x112, 0xF);  // row_shr:2
        S = DPP_ADD(S, 0x114, 0xF);  // row_shr:4
        S = DPP_ADD(S, 0x118, 0xF);  // row_shr:8
        S = DPP_ADD(S, 0x142, 0xA);  // row_bcast:15 -> rows 1,3
        S = DPP_ADD(S, 0x143, 0xC);  // row_bcast:31 -> rows 2,3
        float E = S - T;
        kp0 = 1.0f + E;
        kp1 = 1.0f + E + L0;
        kp2 = 1.0f + E + L1;
        kp3 = 1.0f + E + L2;
    };

    const f32x4_t zero4 = {0.0f, 0.0f, 0.0f, 0.0f};
    const f32x4_t mone4 = {-1.0f, -1.0f, -1.0f, -1.0f};
    const int rb = (lane >> 4) << 2;

    // ---- Block 0: tiles only (no scan yet) ----
    float4 A[4];
    loadA(0, A);
    half8 ah, al;
    makeAhAl(A, ah, al);
    {
        float* __restrict__ wb = incD[0];
#pragma unroll
        for (int t = 0; t < 16; ++t) {
            f32x4_t a2a = __builtin_amdgcn_mfma_f32_16x16x32_f16(
                ah, bl[t], zero4, 0, 0, 0);
            f32x4_t a2b = __builtin_amdgcn_mfma_f32_16x16x32_f16(
                al, bh[t], zero4, 0, 0, 0);
            f32x4_t a1 = __builtin_amdgcn_mfma_f32_16x16x32_f16(
                ah, bh[t], mone4, 0, 0, 0);
            f32x4_t s = a2a + a2b;
            int cc = t * 16 + m16;
            wb[(rb + 0) * 260 + cc] = fmaf(s[0], INV2048, a1[0]);
            wb[(rb + 1) * 260 + cc] = fmaf(s[1], INV2048, a1[1]);
            wb[(rb + 2) * 260 + cc] = fmaf(s[2], INV2048, a1[2]);
            wb[(rb + 3) * 260 + cc] = fmaf(s[3], INV2048, a1[3]);
        }
    }

    // ---- Iterations b=1..15: tile k of block b interleaved with scan row k
    // of block b-1 (scan chain covers MFMA latency + read-hazard window) ----
#pragma clang loop unroll(disable)
    for (int b = 1; b < 16; ++b) {
        loadA(b, A);
        const float4* rp = (const float4*)incD[(b - 1) & 1];
        float* __restrict__ wb = incD[b & 1];
        makeAhAl(A, ah, al);
        float4 w[4];
        w[0] = rp[0 * 65 + lane]; w[1] = rp[1 * 65 + lane];
        w[2] = rp[2 * 65 + lane]; w[3] = rp[3 * 65 + lane];
#pragma unroll
        for (int k = 0; k < 16; ++k) {
            // issue 3 INDEPENDENT MFMAs for tile k
            f32x4_t a2a = __builtin_amdgcn_mfma_f32_16x16x32_f16(
                ah, bl[k], zero4, 0, 0, 0);
            f32x4_t a2b = __builtin_amdgcn_mfma_f32_16x16x32_f16(
                al, bh[k], zero4, 0, 0, 0);
            f32x4_t a1 = __builtin_amdgcn_mfma_f32_16x16x32_f16(
                ah, bh[k], mone4, 0, 0, 0);
            // scan row k of block b-1 under the MFMA shadow
            scan_row(w[k & 3]);
            if (k + 4 < 16) w[k & 3] = rp[(k + 4) * 65 + lane];
            // combine + write tile k (MFMA results now ready)
            f32x4_t s = a2a + a2b;
            int cc = k * 16 + m16;
            wb[(rb + 0) * 260 + cc] = fmaf(s[0], INV2048, a1[0]);
            wb[(rb + 1) * 260 + cc] = fmaf(s[1], INV2048, a1[1]);
            wb[(rb + 2) * 260 + cc] = fmaf(s[2], INV2048, a1[2]);
            wb[(rb + 3) * 260 + cc] = fmaf(s[3], INV2048, a1[3]);
        }
    }

    // ---- Tail: scan block 15, rows 0..14 (inc row 255 doesn't exist) ----
    {
        const float4* rp = (const float4*)incD[1];
        float4 w[4];
        w[0] = rp[0 * 65 + lane]; w[1] = rp[1 * 65 + lane];
        w[2] = rp[2 * 65 + lane]; w[3] = rp[3 * 65 + lane];
#pragma unroll
        for (int k = 0; k < 15; ++k) {
            scan_row(w[k & 3]);
            if (k + 4 < 15) w[k & 3] = rp[(k + 4) * 65 + lane];
        }
    }

    if (lane == 63) {
        // kp3 = K[255][255]
        partial[bid] = (p == 2 ? -2.0f : 1.0f) * kp3;
    }
}

__global__ __launch_bounds__(256) void sig_reduce(const float* __restrict__ partial,
                                                  float* __restrict__ out) {
    const int t = threadIdx.x;
    float v = partial[t] + partial[t + 256] + partial[t + 512];
#pragma unroll
    for (int ofs = 32; ofs > 0; ofs >>= 1) v += __shfl_down(v, ofs);
    __shared__ float ws[4];
    if ((t & 63) == 0) ws[t >> 6] = v;
    __syncthreads();
    if (t == 0) out[0] = (ws[0] + ws[1] + ws[2] + ws[3]) * (1.0f / 256.0f);
}

extern "C" void kernel_launch(void* const* d_in, const int* in_sizes, int n_in,
                              void* d_out, int out_size, void* d_ws, size_t ws_size,
                              hipStream_t stream) {
    const float* X = (const float*)d_in[0];
    const float* Y = (const float*)d_in[1];
    float* partial = (float*)d_ws;       // 768 floats
    sig_pde<<<dim3(768), dim3(64), 0, stream>>>(X, Y, partial);
    sig_reduce<<<dim3(1), dim3(256), 0, stream>>>(partial, (float*)d_out);
}

// Round 21
// 43.118 us; speedup vs baseline: 1.1071x; 1.1071x over previous
//
#include <hip/hip_runtime.h>

// SigLoss: signature kernel PDE, loss = mean_a( K(X,X) + K(Y,Y) - 2 K(X,Y) ).
// A=256, L=256, D=32. One 64-lane wave per (pair,a) problem.
// R21: STATIC double-buffer. R14/R18/R20 indexed incD[(b-1)&1]/incD[b&1] with
// RUNTIME parity -> LLVM cannot prove disjointness -> every block-b ds_write
// ordered before block-(b-1) ds_reads -> the "interleaved" schedules silently
// serialized. Now: two statically distinct __shared__ arrays incA/incB and a
// x2-unrolled main loop, so producer/consumer buffers are compile-time
// different objects (alias-free). Per k: 3 MFMAs (chained acc2) -> scan_row
// (pure VALU/DPP in the MFMA shadow) -> rolling read from the OTHER array ->
// combine+write. B-frags in regs (R18-proven, ~196 VGPR).

typedef _Float16 half8 __attribute__((ext_vector_type(8)));
typedef float f32x4_t __attribute__((ext_vector_type(4)));

#define DPP_ADD(v, ctrl, rmask)                                               \
    ((v) + __int_as_float(__builtin_amdgcn_update_dpp(                        \
               0, __float_as_int(v), (ctrl), (rmask), 0xF, true)))

#define INV2048 4.8828125e-4f

__global__ __launch_bounds__(64)
__attribute__((amdgpu_waves_per_eu(1, 1)))
void sig_pde(const float* __restrict__ X,
             const float* __restrict__ Y,
             float* __restrict__ partial) {
    const int bid = blockIdx.x;
    const int p = bid >> 8;          // 0=xx, 1=yy, 2=xy
    const int a = bid & 255;
    const float* __restrict__ U = (p == 1) ? Y : X;   // rows (i)
    const float* __restrict__ V = (p == 0) ? X : Y;   // cols (j)
    U += (size_t)a * 256 * 32;
    V += (size_t)a * 256 * 32;
    const int lane = threadIdx.x;
    const int m16 = lane & 15;
    const int g2 = (lane >> 4) * 2;

    // Two STATIC buffers: compile-time distinct objects -> alias-free.
    __shared__ __attribute__((aligned(16))) float incA[16 * 260]; // 16.64 KB
    __shared__ __attribute__((aligned(16))) float incB[16 * 260]; // 16.64 KB

    const float4* U4 = (const float4*)U;
    const float4* V4 = (const float4*)V;

    // ---- B fragments dY hi/lo in registers (128 VGPR), R18-verified ----
    half8 bh[16], bl[16];
#pragma unroll
    for (int t = 0; t < 16; ++t) {
        int col = t * 16 + m16;
        int cp = (col + 1 < 256) ? col + 1 : 255;   // col 255 clamps -> dY=0
        float4 lo0 = V4[col * 8 + g2], lo1 = V4[col * 8 + g2 + 1];
        float4 hi0 = V4[cp * 8 + g2],  hi1 = V4[cp * 8 + g2 + 1];
        float d[8] = {hi0.x - lo0.x, hi0.y - lo0.y, hi0.z - lo0.z, hi0.w - lo0.w,
                      hi1.x - lo1.x, hi1.y - lo1.y, hi1.z - lo1.z, hi1.w - lo1.w};
#pragma unroll
        for (int i = 0; i < 8; ++i) {
            _Float16 h = (_Float16)d[i];
            bh[t][i] = h;
            bl[t][i] = (_Float16)((d[i] - (float)h) * 2048.0f);
        }
    }

    // K row state: kp{0..3} = K[r][4*lane+s], row 0 = ones
    float kp0 = 1.0f, kp1 = 1.0f, kp2 = 1.0f, kp3 = 1.0f;

    auto loadA = [&](int blk, float4 (&dst)[4]) {
        int r0 = blk * 16 + m16;
        int r1 = (r0 + 1 < 256) ? r0 + 1 : 255;   // dX[255] := 0 (unscanned)
        dst[0] = U4[r0 * 8 + g2];
        dst[1] = U4[r0 * 8 + g2 + 1];
        dst[2] = U4[r1 * 8 + g2];
        dst[3] = U4[r1 * 8 + g2 + 1];
    };
    auto makeAhAl = [&](const float4 (&src)[4], half8& ah, half8& al) {
        float d[8] = {src[2].x - src[0].x, src[2].y - src[0].y,
                      src[2].z - src[0].z, src[2].w - src[0].w,
                      src[3].x - src[1].x, src[3].y - src[1].y,
                      src[3].z - src[1].z, src[3].w - src[1].w};
#pragma unroll
        for (int i = 0; i < 8; ++i) {
            _Float16 h = (_Float16)d[i];
            ah[i] = h;
            al[i] = (_Float16)((d[i] - (float)h) * 2048.0f);
        }
    };

    auto scan_row = [&](float4 mv) {
        float kn = __int_as_float(__builtin_amdgcn_update_dpp(
            0, __float_as_int(kp0), 0x130 /*wave_shl:1*/, 0xF, 0xF, true));
        float c0 = fmaf(kp0, mv.x, kp1);
        float c1 = fmaf(kp1, mv.y, kp2);
        float c2 = fmaf(kp2, mv.z, kp3);
        float c3 = (lane == 63) ? 0.0f : fmaf(kp3, mv.w, kn);
        float L0 = c0, L1 = L0 + c1, L2 = L1 + c2;
        float T = L2 + c3;
        float S = T;
        S = DPP_ADD(S, 0x111, 0xF);  // row_shr:1
        S = DPP_ADD(S, 0x112, 0xF);  // row_shr:2
        S = DPP_ADD(S, 0x114, 0xF);  // row_shr:4
        S = DPP_ADD(S, 0x118, 0xF);  // row_shr:8
        S = DPP_ADD(S, 0x142, 0xA);  // row_bcast:15 -> rows 1,3
        S = DPP_ADD(S, 0x143, 0xC);  // row_bcast:31 -> rows 2,3
        float E = S - T;
        kp0 = 1.0f + E;
        kp1 = 1.0f + E + L0;
        kp2 = 1.0f + E + L1;
        kp3 = 1.0f + E + L2;
    };

    const f32x4_t zero4 = {0.0f, 0.0f, 0.0f, 0.0f};
    const f32x4_t mone4 = {-1.0f, -1.0f, -1.0f, -1.0f};
    const int rb = (lane >> 4) << 2;

    float4 A[4];
    half8 ah, al;

    // Produce one block into wb (no scan) — used for block 0 only.
    auto produce_only = [&](float* __restrict__ wb) {
#pragma unroll
        for (int t = 0; t < 16; ++t) {
            f32x4_t a2 = __builtin_amdgcn_mfma_f32_16x16x32_f16(
                ah, bl[t], zero4, 0, 0, 0);
            a2 = __builtin_amdgcn_mfma_f32_16x16x32_f16(al, bh[t], a2, 0, 0, 0);
            f32x4_t a1 = __builtin_amdgcn_mfma_f32_16x16x32_f16(
                ah, bh[t], mone4, 0, 0, 0);
            int cc = t * 16 + m16;
            wb[(rb + 0) * 260 + cc] = fmaf(a2[0], INV2048, a1[0]);
            wb[(rb + 1) * 260 + cc] = fmaf(a2[1], INV2048, a1[1]);
            wb[(rb + 2) * 260 + cc] = fmaf(a2[2], INV2048, a1[2]);
            wb[(rb + 3) * 260 + cc] = fmaf(a2[3], INV2048, a1[3]);
        }
    };

    // Produce block (A-frags already in ah/al) into wb while scanning 16 rows
    // from rd. rd/wb are STATICALLY DISTINCT arrays -> reads reorder freely.
    auto phase = [&](const float* __restrict__ rd, float* __restrict__ wb) {
        const float4* rp = (const float4*)rd;     // 65 float4 per row
        float4 w0 = rp[0 * 65 + lane], w1 = rp[1 * 65 + lane];
        float4 w2 = rp[2 * 65 + lane], w3 = rp[3 * 65 + lane];
#pragma unroll
        for (int k = 0; k < 16; ++k) {
            f32x4_t a2 = __builtin_amdgcn_mfma_f32_16x16x32_f16(
                ah, bl[k], zero4, 0, 0, 0);
            a2 = __builtin_amdgcn_mfma_f32_16x16x32_f16(al, bh[k], a2, 0, 0, 0);
            f32x4_t a1 = __builtin_amdgcn_mfma_f32_16x16x32_f16(
                ah, bh[k], mone4, 0, 0, 0);
            // scan row k of previous block (pure VALU/DPP, fills MFMA shadow)
            float4 mv;
            if ((k & 3) == 0) mv = w0;
            else if ((k & 3) == 1) mv = w1;
            else if ((k & 3) == 2) mv = w2;
            else mv = w3;
            scan_row(mv);
            if (k + 4 < 16) {
                float4 nw = rp[(k + 4) * 65 + lane];
                if ((k & 3) == 0) w0 = nw;
                else if ((k & 3) == 1) w1 = nw;
                else if ((k & 3) == 2) w2 = nw;
                else w3 = nw;
            }
            f32x4_t s;
            s[0] = fmaf(a2[0], INV2048, a1[0]);
            s[1] = fmaf(a2[1], INV2048, a1[1]);
            s[2] = fmaf(a2[2], INV2048, a1[2]);
            s[3] = fmaf(a2[3], INV2048, a1[3]);
            int cc = k * 16 + m16;
            wb[(rb + 0) * 260 + cc] = s[0];
            wb[(rb + 1) * 260 + cc] = s[1];
            wb[(rb + 2) * 260 + cc] = s[2];
            wb[(rb + 3) * 260 + cc] = s[3];
        }
    };

    // Scan-only 16 (or 15) rows from rd.
    auto scan_tail = [&](const float* __restrict__ rd) {
        const float4* rp = (const float4*)rd;
        float4 w0 = rp[0 * 65 + lane], w1 = rp[1 * 65 + lane];
        float4 w2 = rp[2 * 65 + lane], w3 = rp[3 * 65 + lane];
#pragma unroll
        for (int k = 0; k < 15; ++k) {
            float4 mv;
            if ((k & 3) == 0) mv = w0;
            else if ((k & 3) == 1) mv = w1;
            else if ((k & 3) == 2) mv = w2;
            else mv = w3;
            scan_row(mv);
            if (k + 4 < 15) {
                float4 nw = rp[(k + 4) * 65 + lane];
                if ((k & 3) == 0) w0 = nw;
                else if ((k & 3) == 1) w1 = nw;
                else if ((k & 3) == 2) w2 = nw;
                else w3 = nw;
            }
        }
    };

    // ---- Main: block 0 -> incA; then pairs with static buffer roles ----
    loadA(0, A);
    makeAhAl(A, ah, al);
    loadA(1, A);
    produce_only(incA);                       // block 0

#pragma clang loop unroll(disable)
    for (int bb = 0; bb < 7; ++bb) {          // blocks (2bb+1, 2bb+2)
        makeAhAl(A, ah, al);
        loadA(2 * bb + 2, A);
        phase(incA, incB);                    // produce 2bb+1, scan 2bb
        makeAhAl(A, ah, al);
        loadA(2 * bb + 3, A);
        phase(incB, incA);                    // produce 2bb+2, scan 2bb+1
    }
    makeAhAl(A, ah, al);
    phase(incA, incB);                        // produce 15, scan 14
    scan_tail(incB);                          // scan block 15 (15 rows)

    if (lane == 63) {
        // kp3 = K[255][255]
        partial[bid] = (p == 2 ? -2.0f : 1.0f) * kp3;
    }
}

__global__ __launch_bounds__(256) void sig_reduce(const float* __restrict__ partial,
                                                  float* __restrict__ out) {
    const int t = threadIdx.x;
    float v = partial[t] + partial[t + 256] + partial[t + 512];
#pragma unroll
    for (int ofs = 32; ofs > 0; ofs >>= 1) v += __shfl_down(v, ofs);
    __shared__ float ws[4];
    if ((t & 63) == 0) ws[t >> 6] = v;
    __syncthreads();
    if (t == 0) out[0] = (ws[0] + ws[1] + ws[2] + ws[3]) * (1.0f / 256.0f);
}

extern "C" void kernel_launch(void* const* d_in, const int* in_sizes, int n_in,
                              void* d_out, int out_size, void* d_ws, size_t ws_size,
                              hipStream_t stream) {
    const float* X = (const float*)d_in[0];
    const float* Y = (const float*)d_in[1];
    float* partial = (float*)d_ws;       // 768 floats
    sig_pde<<<dim3(768), dim3(64), 0, stream>>>(X, Y, partial);
    sig_reduce<<<dim3(1), dim3(256), 0, stream>>>(partial, (float*)d_out);
}